// Round 6
// baseline (262.392 us; speedup 1.0000x reference)
//
#include <hip/hip_runtime.h>

// MultiHead attention, B=2 S=2048 D=1024 H=16 HD=64, fp32 in/out, bf16 MFMA internally.
// Reference bug reproduced: Q is projected with Wk/bk.

#define Bn 2
#define Sn 2048
#define Dn 1024
#define Hn 16
#define HDn 64

typedef short bs8 __attribute__((ext_vector_type(8)));   // 8 x bf16 (raw bits)
typedef float f32x4 __attribute__((ext_vector_type(4)));
typedef float f32x16 __attribute__((ext_vector_type(16)));
typedef unsigned int u32;
typedef unsigned int u32x2 __attribute__((ext_vector_type(2)));
typedef unsigned int u32x4 __attribute__((ext_vector_type(4)));

__device__ __forceinline__ short f2bf(float f) {
    u32 x = __builtin_bit_cast(u32, f);
    x = x + 0x7fffu + ((x >> 16) & 1u);   // RNE
    return (short)(x >> 16);
}
// packed f32x2 -> bf16x2 in one VALU op (RNE, matches f2bf)
__device__ __forceinline__ u32 cvtpk(float lo, float hi) {
    u32 r;
    asm("v_cvt_pk_bf16_f32 %0, %1, %2" : "=v"(r) : "v"(lo), "v"(hi));
    return r;
}
// permlane32_swap via builtin: r[0] = [a.lo | b.lo], r[1] = [a.hi | b.hi]
// (builtin models cross-lane dataflow; asm version could coalesce a==b into one reg)
__device__ __forceinline__ u32x2 pl32swap(u32 a, u32 b) {
    return __builtin_amdgcn_permlane32_swap(a, b, false, false);
}
__device__ __forceinline__ float asf(u32 x) { return __builtin_bit_cast(float, x); }
__device__ __forceinline__ u32 asu(float x) { return __builtin_bit_cast(u32, x); }
__device__ __forceinline__ void gload16(const void* g, void* l) {
    __builtin_amdgcn_global_load_lds(
        (const __attribute__((address_space(1))) u32*)g,
        (__attribute__((address_space(3))) u32*)l, 16, 0, 0);
}

// ---- fp32 q/k/v -> bf16, z-fused ----
__global__ __launch_bounds__(256) void cvt_qkv(const float* __restrict__ q,
                                               const float* __restrict__ k,
                                               const float* __restrict__ v,
                                               short* __restrict__ out) {
    int z = blockIdx.y;
    const float* in = z == 0 ? q : z == 1 ? k : v;
    short* o = out + (size_t)z * (Bn * Sn * Dn);
    int i = blockIdx.x * 256 + threadIdx.x;
    const f32x4* p = reinterpret_cast<const f32x4*>(in) + (size_t)i * 2;
    f32x4 a = p[0], b = p[1];
    bs8 ov;
    ov[0]=f2bf(a[0]); ov[1]=f2bf(a[1]); ov[2]=f2bf(a[2]); ov[3]=f2bf(a[3]);
    ov[4]=f2bf(b[0]); ov[5]=f2bf(b[1]); ov[6]=f2bf(b[2]); ov[7]=f2bf(b[3]);
    reinterpret_cast<bs8*>(o)[i] = ov;
}

// ---- W [K][N] fp32 -> Wt [N][K] bf16 (tiled transpose), z-fused ----
__global__ __launch_bounds__(256) void cvt_w(const float* __restrict__ Wk,
                                             const float* __restrict__ Wv,
                                             const float* __restrict__ Wo,
                                             short* __restrict__ Wt) {
    __shared__ float tile[32][33];
    int z = blockIdx.z;
    const float* W = z == 0 ? Wk : z == 1 ? Wv : Wo;
    short* o = Wt + (size_t)z * Dn * Dn;
    int tx = threadIdx.x & 31;
    int ty = threadIdx.x >> 5;
    int bi = blockIdx.y * 32;
    int bo = blockIdx.x * 32;
    #pragma unroll
    for (int k2 = 0; k2 < 4; k2++)
        tile[ty + k2*8][tx] = W[(size_t)(bi + ty + k2*8) * Dn + bo + tx];
    __syncthreads();
    #pragma unroll
    for (int k2 = 0; k2 < 4; k2++)
        o[(size_t)(bo + ty + k2*8) * Dn + bi + tx] = f2bf(tile[tx][ty + k2*8]);
}

// ---- Fused projection GEMMs (z-batched): 128x128 tile, BK=32 ----
// z=0: Qp = (q@Wk+bk)*log2(e)/8 ; z=1: Kp = k@Wk+bk ; z=2: Vtp = (v@Wv+bv)^T [B][D][S]
__global__ __launch_bounds__(256) void proj3(const short* __restrict__ qb,
                                             const short* __restrict__ kb,
                                             const short* __restrict__ vb,
                                             const short* __restrict__ Wall,
                                             const float* __restrict__ bk,
                                             const float* __restrict__ bv,
                                             short* __restrict__ Qp,
                                             short* __restrict__ Kp,
                                             short* __restrict__ Vtp) {
    constexpr int K = Dn;
    __shared__ __align__(16) short As[128 * 32];
    __shared__ __align__(16) short Bs[128 * 32];
    int z = blockIdx.z;
    const short* A  = z == 0 ? qb : z == 1 ? kb : vb;
    const short* Bt = z == 2 ? Wall + (1 << 20) : Wall;
    const float* bias = z == 2 ? bv : bk;
    int tid = threadIdx.x;
    int m0 = blockIdx.x * 128, n0 = blockIdx.y * 128;
    int w = tid >> 6, lane = tid & 63;
    int wr = (w >> 1) * 64, wc = (w & 1) * 64;
    int fr = lane & 15, fq = lane >> 4;
    f32x4 acc[4][4] = {};
    const short* Ag  = A  + (size_t)(m0 + (tid >> 2)) * K + (tid & 3) * 8;
    const short* Ag2 = Ag + (size_t)64 * K;
    const short* Bg  = Bt + (size_t)(n0 + (tid >> 2)) * K + (tid & 3) * 8;
    const short* Bg2 = Bg + (size_t)64 * K;
    short* AsL = As + tid * 8;
    short* BsL = Bs + tid * 8;

    for (int k0 = 0; k0 < K; k0 += 32) {
        gload16(Ag + k0, AsL);
        gload16(Ag2 + k0, AsL + 2048);
        gload16(Bg + k0, BsL);
        gload16(Bg2 + k0, BsL + 2048);
        __syncthreads();                      // drains vmcnt: tiles landed
        bs8 af[4], bfv[4];
        #pragma unroll
        for (int i = 0; i < 4; i++)
            af[i] = *reinterpret_cast<const bs8*>(&As[(wr + i*16 + fr) * 32 + fq * 8]);
        #pragma unroll
        for (int j = 0; j < 4; j++)
            bfv[j] = *reinterpret_cast<const bs8*>(&Bs[(wc + j*16 + fr) * 32 + fq * 8]);
        #pragma unroll
        for (int i = 0; i < 4; i++)
            #pragma unroll
            for (int j = 0; j < 4; j++)
                acc[i][j] = __builtin_amdgcn_mfma_f32_16x16x32_bf16(af[i], bfv[j], acc[i][j], 0, 0, 0);
        __syncthreads();
    }

    if (z == 2) {
        #pragma unroll
        for (int j = 0; j < 4; j++) {
            int col = n0 + wc + j*16 + fr;
            float bvv = bias[col];
            #pragma unroll
            for (int i = 0; i < 4; i++) {
                int row0 = m0 + wr + i*16 + fq*4;
                int bb = row0 >> 11, s0 = row0 & (Sn - 1);
                size_t base = (size_t)bb * (Dn * Sn) + (size_t)col * Sn + s0;
                u32x2 pv;
                pv[0] = cvtpk(acc[i][j][0] + bvv, acc[i][j][1] + bvv);
                pv[1] = cvtpk(acc[i][j][2] + bvv, acc[i][j][3] + bvv);
                *reinterpret_cast<u32x2*>(&Vtp[base]) = pv;
            }
        }
    } else {
        float sc = (z == 0) ? 0.18033688011112042f : 1.0f;   // log2(e)/8 folded into Qp
        short* outp = (z == 0) ? Qp : Kp;
        #pragma unroll
        for (int j = 0; j < 4; j++) {
            int col = n0 + wc + j*16 + fr;
            float bvv = bias[col];
            #pragma unroll
            for (int i = 0; i < 4; i++) {
                int row0 = m0 + wr + i*16 + fq*4;
                #pragma unroll
                for (int r = 0; r < 4; r++)
                    outp[(size_t)(row0 + r) * Dn + col] = f2bf((acc[i][j][r] + bvv) * sc);
            }
        }
    }
}

// ---- out-proj GEMM: C[4096][1024] fp32 = A(bf16) @ Bt^T + bias ----
__global__ __launch_bounds__(256) void gemm_out(const short* __restrict__ A,
                                                const short* __restrict__ Bt,
                                                const float* __restrict__ bias,
                                                float* __restrict__ Cout) {
    constexpr int K = Dn, N = Dn;
    __shared__ __align__(16) short As[64][32];
    __shared__ __align__(16) short Bs[128][32];
    int tid = threadIdx.x;
    int m0 = blockIdx.x * 64, n0 = blockIdx.y * 128;
    int w = tid >> 6, lane = tid & 63;
    int wr = (w >> 1) * 32, wc = (w & 1) * 64;
    int fr = lane & 15, fq = lane >> 4;
    f32x4 acc[2][4] = {};
    const short* Ag  = A  + (size_t)(m0 + (tid >> 2)) * K + (tid & 3) * 8;
    const short* Bg0 = Bt + (size_t)(n0 + (tid >> 2)) * K + (tid & 3) * 8;
    const short* Bg1 = Bg0 + (size_t)64 * K;
    short* AsL  = &As[0][0] + tid * 8;
    short* BsL0 = &Bs[0][0] + tid * 8;
    short* BsL1 = BsL0 + 2048;

    for (int k0 = 0; k0 < K; k0 += 32) {
        gload16(Ag + k0, AsL);
        gload16(Bg0 + k0, BsL0);
        gload16(Bg1 + k0, BsL1);
        __syncthreads();
        bs8 af[2], bfv[4];
        #pragma unroll
        for (int i = 0; i < 2; i++)
            af[i] = *reinterpret_cast<const bs8*>(&As[wr + i*16 + fr][fq*8]);
        #pragma unroll
        for (int j = 0; j < 4; j++)
            bfv[j] = *reinterpret_cast<const bs8*>(&Bs[wc + j*16 + fr][fq*8]);
        #pragma unroll
        for (int i = 0; i < 2; i++)
            #pragma unroll
            for (int j = 0; j < 4; j++)
                acc[i][j] = __builtin_amdgcn_mfma_f32_16x16x32_bf16(af[i], bfv[j], acc[i][j], 0, 0, 0);
        __syncthreads();
    }
    #pragma unroll
    for (int j = 0; j < 4; j++) {
        int col = n0 + wc + j*16 + fr;
        float bv = bias[col];
        #pragma unroll
        for (int i = 0; i < 2; i++) {
            int row0 = m0 + wr + i*16 + fq*4;
            #pragma unroll
            for (int r = 0; r < 4; r++)
                Cout[(size_t)(row0 + r) * N + col] = acc[i][j][r] + bv;
        }
    }
}

// ---- Flash attention, 32x32 MFMA, swapped QK^T, lane-local softmax/P ----
// Qp pre-scaled by log2(e)/8. Kp [B*S][D] bf16; Vt [B][D][S] bf16.
// grid (16, B*H); qt = 15 - bx (heavy first). 4 waves; wave w owns q rows
// qt*128 + 32w .. +31; lane's q = lane&31 (lane and lane^32 share a q-row).
__global__ __launch_bounds__(256) void attn_fwd(const short* __restrict__ Qp,
                                                const short* __restrict__ Kp,
                                                const short* __restrict__ Vt,
                                                short* __restrict__ O) {
    __shared__ __align__(16) char Kb[64 * 128];   // [kv][64d], rows XOR-swizzled
    __shared__ __align__(16) char Vb[64 * 128];   // [d][64kv], rows XOR-swizzled
    __shared__ __align__(16) u32 Ot[4][32 * 36];  // per-wave O^T -> O transpose
    int qt = 15 - (int)blockIdx.x;
    int bh = blockIdx.y, bb = bh >> 4, h = bh & 15;
    int tid = threadIdx.x, w = tid >> 6, lane = tid & 63;
    int lq = lane & 31, hi = lane >> 5;
    int q0 = qt * 128 + w * 32;                   // wave q base (seq-local)
    int qg = q0 + lq;                             // lane's q row
    int qw_end = q0 + 31;

    // Q fragments: Q[q=lq][d=16t+8hi+j], 4x bs8 (16 VGPR)
    const short* Qrow = Qp + (size_t)(bb * Sn + qg) * Dn + h * HDn;
    bs8 qf[4];
    #pragma unroll
    for (int t = 0; t < 4; t++)
        qf[t] = *reinterpret_cast<const bs8*>(Qrow + 16 * t + 8 * hi);

    f32x16 oacc0 = {}, oacc1 = {};                // O^T[d=crow(r,hi)+32m][q=lq]
    float m_run = -3e38f, l_run = 0.f;

    // staging: wave w stages rows 16w..16w+15 (2 passes of 8 rows), 16B/lane,
    // global source col pre-swizzled so LDS is linear (m173 pattern).
    int srow = 16 * w + (lane >> 3);
    int scol = (8 * (lane & 7)) ^ ((lane >> 3) << 3);   // shorts, within 64-elem row
    const short* KgB = Kp + (size_t)(bb * Sn + srow) * Dn + h * HDn + scol;
    const short* VgB = Vt + (size_t)bb * (Dn * Sn) + (size_t)(h * HDn + srow) * Sn + scol;
    char* KdA = Kb + (16 * w) * 128;
    char* KdB = KdA + 8 * 128;
    char* VdA = Vb + (16 * w) * 128;
    char* VdB = VdA + 8 * 128;

    int rsw = (lq & 7) << 4;                      // compute-side swizzle (row&7)<<4
    const char* Krow0 = Kb + lq * 128;
    const char* Krow1 = Kb + (32 + lq) * 128;
    const char* Vrow0 = Vb + lq * 128;
    const char* Vrow1 = Vb + (32 + lq) * 128;

    int nkv = 2 * qt + 2;
    for (int kt = 0; kt < nkv; kt++) {
        int kv0 = kt * 64;
        __syncthreads();                          // prior tile's LDS reads done
        gload16(KgB + (size_t)kv0 * Dn, KdA);
        gload16(KgB + (size_t)kv0 * Dn + 8 * Dn, KdB);
        gload16(VgB + kv0, VdA);
        gload16(VgB + kv0 + 8 * Sn, VdB);
        __syncthreads();                          // vmcnt drained: tile landed
        if (kv0 > qw_end) continue;               // fully masked for this wave

        // S^T = K Q^T (log2 units): s{0,1}[r] = S[kv0+32m+crow(r,hi)][q=lq]
        f32x16 s0 = {}, s1 = {};
        #pragma unroll
        for (int t = 0; t < 4; t++) {
            int ofs = (32 * t + 16 * hi) ^ rsw;
            bs8 kf0 = *reinterpret_cast<const bs8*>(Krow0 + ofs);
            bs8 kf1 = *reinterpret_cast<const bs8*>(Krow1 + ofs);
            s0 = __builtin_amdgcn_mfma_f32_32x32x16_bf16(kf0, qf[t], s0, 0, 0, 0);
            s1 = __builtin_amdgcn_mfma_f32_32x32x16_bf16(kf1, qf[t], s1, 0, 0, 0);
        }
        if (kv0 + 63 > q0) {                      // causal mask (partial tiles)
            #pragma unroll
            for (int r = 0; r < 16; r++) {
                int c = (r & 3) + 8 * (r >> 2) + 4 * hi;
                if (kv0 + c > qg)      s0[r] = -1.8e8f;
                if (kv0 + 32 + c > qg) s1[r] = -1.8e8f;
            }
        }

        // online softmax: in-register + one permlane32_swap; defer-max THR=8
        float mloc = fmaxf(s0[0], s1[0]);
        #pragma unroll
        for (int r = 1; r < 16; r++) mloc = fmaxf(mloc, fmaxf(s0[r], s1[r]));
        {
            u32x2 rr = pl32swap(asu(mloc), asu(mloc));
            mloc = fmaxf(asf(rr[0]), asf(rr[1]));   // max(own-half, other-half)
        }
        if (!__all(mloc <= m_run + 8.0f)) {
            float mn = fmaxf(m_run, mloc);
            float fac = exp2f(m_run - mn);
            m_run = mn; l_run *= fac;
            oacc0 *= fac; oacc1 *= fac;
        }
        float ss = 0.f;
        #pragma unroll
        for (int r = 0; r < 16; r++) {
            s0[r] = exp2f(s0[r] - m_run); ss += s0[r];
            s1[r] = exp2f(s1[r] - m_run); ss += s1[r];
        }
        l_run += ss;                              // per-lane partial

        // P^T -> PV B-frags, in-register: 16 cvt_pk + 8 permlane32_swap.
        // W[b][u] = bf16 pair at kv = 32b + 8(u>>1) + 2(u&1) + 4hi.
        u32 W0[8], W1[8];
        #pragma unroll
        for (int u = 0; u < 8; u++) {
            W0[u] = cvtpk(s0[2*u], s0[2*u+1]);
            W1[u] = cvtpk(s1[2*u], s1[2*u+1]);
        }
        // chain t (kv 16t..16t+15): B-frag words = pairs at kv 16t+8hi+{0,2,4,6}
        u32x4 Bf[4];
        #pragma unroll
        for (int t = 0; t < 4; t++) {
            int u0 = 4 * (t & 1);
            u32 a0 = (t < 2) ? W0[u0]     : W1[u0];
            u32 b0 = (t < 2) ? W0[u0 + 2] : W1[u0 + 2];
            u32 a1 = (t < 2) ? W0[u0 + 1] : W1[u0 + 1];
            u32 b1 = (t < 2) ? W0[u0 + 3] : W1[u0 + 3];
            u32x2 r0 = pl32swap(a0, b0);
            u32x2 r1 = pl32swap(a1, b1);
            Bf[t][0] = r0[0]; Bf[t][1] = r1[0]; Bf[t][2] = r0[1]; Bf[t][3] = r1[1];
        }

        // O^T += V^T P^T
        #pragma unroll
        for (int t = 0; t < 4; t++) {
            bs8 pB = __builtin_bit_cast(bs8, Bf[t]);
            int ofs = (32 * t + 16 * hi) ^ rsw;
            bs8 vf0 = *reinterpret_cast<const bs8*>(Vrow0 + ofs);
            bs8 vf1 = *reinterpret_cast<const bs8*>(Vrow1 + ofs);
            oacc0 = __builtin_amdgcn_mfma_f32_32x32x16_bf16(vf0, pB, oacc0, 0, 0, 0);
            oacc1 = __builtin_amdgcn_mfma_f32_32x32x16_bf16(vf1, pB, oacc1, 0, 0, 0);
        }
    }

    // combine l across the lane/lane^32 split
    {
        u32x2 rr = pl32swap(asu(l_run), asu(l_run));
        l_run = asf(rr[0]) + asf(rr[1]);
    }
    float inv = 1.f / l_run;

    // O^T -> O via per-wave LDS tile (stride 36 words; 16B-aligned rows)
    u32* OtW = Ot[w];
    #pragma unroll
    for (int m = 0; m < 2; m++) {
        f32x16 oo = m ? oacc1 : oacc0;
        #pragma unroll
        for (int u = 0; u < 8; u += 2) {
            u32x2 wv;
            wv[0] = cvtpk(oo[2*u] * inv,     oo[2*u+1] * inv);
            wv[1] = cvtpk(oo[2*u+2] * inv,   oo[2*u+3] * inv);
            int widx = 16 * m + 4 * (u >> 1) + 2 * hi;   // d-pair index
            *reinterpret_cast<u32x2*>(OtW + lq * 36 + widx) = wv;
        }
    }
    __builtin_amdgcn_wave_barrier();              // wave-private tile; order only
    int q2 = lane >> 1, hh = lane & 1;
    const u32* rp = OtW + q2 * 36 + hh * 16;
    short* Og = O + (size_t)(bb * Sn + q0 + q2) * Dn + h * HDn + hh * 32;
    #pragma unroll
    for (int c = 0; c < 4; c++) {
        u32x4 vv = *reinterpret_cast<const u32x4*>(rp + 4 * c);
        *reinterpret_cast<u32x4*>(Og + 8 * c) = vv;
    }
}

extern "C" void kernel_launch(void* const* d_in, const int* in_sizes, int n_in,
                              void* d_out, int out_size, void* d_ws, size_t ws_size,
                              hipStream_t stream) {
    const float* q  = (const float*)d_in[0];
    const float* k  = (const float*)d_in[1];
    const float* v  = (const float*)d_in[2];
    // d_in[3] = mask (causal; implemented analytically)
    const float* Wk = (const float*)d_in[4];
    const float* bk = (const float*)d_in[5];
    const float* Wv = (const float*)d_in[6];
    const float* bv = (const float*)d_in[7];
    const float* Wo = (const float*)d_in[8];
    const float* bo = (const float*)d_in[9];

    char* ws = (char*)d_ws;
    const size_t MB = (size_t)1 << 20;
    short* Wall = (short*)ws;                 // Wkt | Wvt | Wot, 2MB each (bf16 [N][K])
    short* Wot  = Wall + 2 * (1 << 20);
    short* qb   = (short*)(ws + 6*MB);        // 8MB each
    short* kb   = (short*)(ws + 14*MB);
    short* vb   = (short*)(ws + 22*MB);
    short* Qp   = (short*)(ws + 30*MB);
    short* Kp   = (short*)(ws + 38*MB);
    short* Vtp  = (short*)(ws + 46*MB);       // [B][D][S]
    short* Oa   = qb;                         // qb dead after proj3

    cvt_qkv<<<dim3(2048, 3), dim3(256), 0, stream>>>(q, k, v, qb);
    cvt_w<<<dim3(32, 32, 3), dim3(256), 0, stream>>>(Wk, Wv, Wo, Wall);

    proj3<<<dim3(32, 8, 3), dim3(256), 0, stream>>>(qb, kb, vb, Wall, bk, bv, Qp, Kp, Vtp);

    attn_fwd<<<dim3(16, 32), dim3(256), 0, stream>>>(Qp, Kp, Vtp, Oa);

    gemm_out<<<dim3(64, 8), dim3(256), 0, stream>>>(Oa, Wot, bo, (float*)d_out);
}